// Round 1
// baseline (18787.225 us; speedup 1.0000x reference)
//
#include <hip/hip_runtime.h>

typedef _Float16 f16x8 __attribute__((ext_vector_type(8)));
typedef float    f32x4 __attribute__((ext_vector_type(4)));

constexpr int BATCH = 1024;
constexpr int HDIM  = 512;
constexpr int TENC  = 512;
constexpr int PRED  = 48;
constexpr int STEPS = TENC + PRED - 1;   // 559 cell steps (last decode cell unused)
constexpr int NGRP  = 32;                // independent batch groups
constexpr int GBAT  = 32;                // batches per group
constexpr int NUB   = 8;                 // unit-blocks per group
constexpr int UBU   = 64;                // units per block
constexpr int HB_OFF = 4096;             // hbuf offset in ws (bytes)

struct __align__(64) Bar { int count; int gen; int pad[14]; };

// d_ws / d_out are poisoned 0xAA before every launch: zero barrier state,
// h ping-pong buffer 0, and d_out (it accumulates fc partials via atomics).
__global__ void init_kernel(int* wsi, float* out) {
  int idx = blockIdx.x * blockDim.x + threadIdx.x;
  int stride = gridDim.x * blockDim.x;
  const int nws = (HB_OFF + BATCH * HDIM * 2) / 4;  // bars + hbuf[0] (1 MB fp16)
  for (int i = idx; i < nws; i += stride) wsi[i] = 0;
  for (int i = idx; i < BATCH * PRED; i += stride) out[i] = 0.f;
}

__global__ __launch_bounds__(256, 1) void lstm_persist(
    const float* __restrict__ x,
    const float* __restrict__ w_ih,
    const float* __restrict__ w_hh,
    const float* __restrict__ b_ih,
    const float* __restrict__ b_hh,
    const float* __restrict__ w_fc,
    const float* __restrict__ b_fc,
    float* __restrict__ out,          // [1024][48] fp32; also decode input
    _Float16* __restrict__ hbuf,      // [2][1024][512] fp16 ping-pong
    Bar* __restrict__ bars)           // [32] group barriers
{
  const int bid  = blockIdx.x;
  const int grp  = bid & (NGRP - 1);  // group = bid%32 -> group's 8 blocks share XCD (heuristic)
  const int ub   = bid >> 5;          // unit-block 0..7
  const int tid  = threadIdx.x;
  const int wid  = tid >> 6;          // wave 0..3
  const int lane = tid & 63;
  const int quad = lane >> 4;
  const int lcol = lane & 15;
  const int b0   = grp * GBAT;
  const int myu  = ub * UBU + wid * 16 + lcol;   // this lane's hidden unit

  // h tile: 32 batches x 512 k, fp16, pitch 520 (pad 8 -> 2-way bank alias only)
  __shared__ __align__(16) _Float16 hs[GBAT][520];

  // ---- one-time: load this wave's weight tile as register B-fragments ----
  // B-frag layout (16x16x32): n = lane&15 (gate row), k = kc*32 + quad*8 + j
  f16x8 wf[4][16];
  float wih[4], bias[4];
#pragma unroll
  for (int nt = 0; nt < 4; ++nt) {         // gate type i,f,g,o
    const int j = nt * HDIM + myu;         // row in w_hh [2048][512]
    wih[nt]  = w_ih[j];
    bias[nt] = b_ih[j] + b_hh[j];
#pragma unroll
    for (int kc = 0; kc < 16; ++kc) {
      const float* s = w_hh + (size_t)j * HDIM + kc * 32 + quad * 8;
      f16x8 v;
#pragma unroll
      for (int i = 0; i < 8; ++i) v[i] = (_Float16)s[i];
      wf[nt][kc] = v;
    }
  }
  const float wfc = w_fc[myu];
  const float bfc = b_fc[0];

  float cst[2][4];                         // persistent cell state (8 cells/lane)
#pragma unroll
  for (int mt = 0; mt < 2; ++mt)
#pragma unroll
    for (int r = 0; r < 4; ++r) cst[mt][r] = 0.f;

  Bar* bar = &bars[grp];

  for (int t = 0; t < STEPS; ++t) {
    const _Float16* hcur = hbuf + (size_t)(t & 1) * BATCH * HDIM;
    _Float16*       hnxt = hbuf + (size_t)((t + 1) & 1) * BATCH * HDIM;

    // ---- stage h[b0..b0+31][0..511] into LDS (fp16x8 vector loads) ----
#pragma unroll
    for (int i = 0; i < 8; ++i) {
      const int e   = tid + i * 256;       // 0..2047 chunks of 8 halves
      const int row = e >> 6;
      const int c8  = e & 63;
      f16x8 v = *reinterpret_cast<const f16x8*>(
          hcur + (size_t)(b0 + row) * HDIM + c8 * 8);
      *reinterpret_cast<f16x8*>(&hs[row][c8 * 8]) = v;
    }
    __syncthreads();

    // ---- GEMM: acc[mt][nt] = h(32x512) @ w_tile.T ----
    f32x4 acc[2][4];
#pragma unroll
    for (int mt = 0; mt < 2; ++mt)
#pragma unroll
      for (int nt = 0; nt < 4; ++nt) acc[mt][nt] = (f32x4){0.f, 0.f, 0.f, 0.f};

#pragma unroll
    for (int kc = 0; kc < 16; ++kc) {
      // A-frag: m = lane&15 (+16*mt), k = kc*32 + quad*8 + j
      f16x8 a0 = *reinterpret_cast<const f16x8*>(&hs[lcol][kc * 32 + quad * 8]);
      f16x8 a1 = *reinterpret_cast<const f16x8*>(&hs[16 + lcol][kc * 32 + quad * 8]);
#pragma unroll
      for (int nt = 0; nt < 4; ++nt) {
        acc[0][nt] = __builtin_amdgcn_mfma_f32_16x16x32_f16(a0, wf[nt][kc], acc[0][nt], 0, 0, 0);
        acc[1][nt] = __builtin_amdgcn_mfma_f32_16x16x32_f16(a1, wf[nt][kc], acc[1][nt], 0, 0, 0);
      }
    }

    // ---- cell update, all 4 gates in-lane (C-layout: col=lane&15, row=quad*4+r) ----
    float hnew[2][4];
#pragma unroll
    for (int mt = 0; mt < 2; ++mt) {
#pragma unroll
      for (int r = 0; r < 4; ++r) {
        const int b = b0 + mt * 16 + quad * 4 + r;
        const float xt = (t < TENC) ? x[(size_t)b * TENC + t]
                                    : out[b * PRED + (t - TENC)];
        const float gi = acc[mt][0][r] + xt * wih[0] + bias[0];
        const float gf = acc[mt][1][r] + xt * wih[1] + bias[1];
        const float gg = acc[mt][2][r] + xt * wih[2] + bias[2];
        const float go = acc[mt][3][r] + xt * wih[3] + bias[3];
        const float si = 1.f / (1.f + __expf(-gi));
        const float sf = 1.f / (1.f + __expf(-gf));
        const float so = 1.f / (1.f + __expf(-go));
        const float tg = 1.f - 2.f / (1.f + __expf(2.f * gg));   // tanh
        const float cn = sf * cst[mt][r] + si * tg;
        cst[mt][r] = cn;
        const float tc = 1.f - 2.f / (1.f + __expf(2.f * cn));   // tanh
        const float hn = so * tc;
        hnew[mt][r] = hn;
        hnxt[(size_t)b * HDIM + myu] = (_Float16)hn;             // fp16 for next GEMM
      }
    }

    // ---- fc(h) for decode steps: quad-wide reduce over 16 units + atomic ----
    if (t >= TENC - 1) {
      const int p = t - (TENC - 1);
#pragma unroll
      for (int mt = 0; mt < 2; ++mt) {
#pragma unroll
        for (int r = 0; r < 4; ++r) {
          float v = hnew[mt][r] * wfc;     // fp32 h for accuracy
          v += __shfl_xor(v, 1);
          v += __shfl_xor(v, 2);
          v += __shfl_xor(v, 4);
          v += __shfl_xor(v, 8);
          if (lcol == 0) {
            const int b = b0 + mt * 16 + quad * 4 + r;
            const float add = v + ((ub == 0 && wid == 0) ? bfc : 0.f);
            atomicAdd(&out[b * PRED + p], add);
          }
        }
      }
    }

    // ---- group-local (8-block) barrier ----
    __threadfence();      // publish h/out stores device-wide
    __syncthreads();
    if (tid == 0) {
      const int target = t + 1;
      int old = __hip_atomic_fetch_add(&bar->count, 1, __ATOMIC_ACQ_REL,
                                       __HIP_MEMORY_SCOPE_AGENT);
      if (old == NUB - 1) {
        __hip_atomic_store(&bar->count, 0, __ATOMIC_RELAXED, __HIP_MEMORY_SCOPE_AGENT);
        __hip_atomic_fetch_add(&bar->gen, 1, __ATOMIC_RELEASE, __HIP_MEMORY_SCOPE_AGENT);
      } else {
        while (__hip_atomic_load(&bar->gen, __ATOMIC_ACQUIRE,
                                 __HIP_MEMORY_SCOPE_AGENT) < target)
          __builtin_amdgcn_s_sleep(1);
      }
    }
    __syncthreads();
  }
}

extern "C" void kernel_launch(void* const* d_in, const int* in_sizes, int n_in,
                              void* d_out, int out_size, void* d_ws, size_t ws_size,
                              hipStream_t stream) {
  const float* x    = (const float*)d_in[0];
  const float* w_ih = (const float*)d_in[1];
  const float* w_hh = (const float*)d_in[2];
  const float* b_ih = (const float*)d_in[3];
  const float* b_hh = (const float*)d_in[4];
  const float* w_fc = (const float*)d_in[5];
  const float* b_fc = (const float*)d_in[6];
  float* out = (float*)d_out;
  Bar* bars = (Bar*)d_ws;
  _Float16* hbuf = (_Float16*)((char*)d_ws + HB_OFF);

  hipLaunchKernelGGL(init_kernel, dim3(256), dim3(256), 0, stream, (int*)d_ws, out);
  hipLaunchKernelGGL(lstm_persist, dim3(NGRP * NUB), dim3(256), 0, stream,
                     x, w_ih, w_hh, b_ih, b_hh, w_fc, b_fc, out, hbuf, bars);
}

// Round 2
// 3624.322 us; speedup vs baseline: 5.1837x; 5.1837x over previous
//
#include <hip/hip_runtime.h>

typedef _Float16 f16x8 __attribute__((ext_vector_type(8)));
typedef float    f32x4 __attribute__((ext_vector_type(4)));
typedef unsigned long long u64;

constexpr int BATCH = 1024;
constexpr int HDIM  = 512;
constexpr int TENC  = 512;
constexpr int PRED  = 48;
constexpr int STEPS = TENC + PRED - 1;   // 559 cell steps
constexpr int NGRP  = 32;                // independent batch groups
constexpr int GBAT  = 32;                // batches per group
constexpr int NUB   = 8;                 // unit-blocks per group
constexpr int UBU   = 64;                // units per block
constexpr int HB_OFF = 4096;             // hbuf offset in ws (bytes)

struct __align__(64) Bar { int count; int gen; int pad[14]; };

// d_ws / d_out are poisoned 0xAA before every launch: zero barrier state,
// h ping-pong buffer 0, and d_out (it accumulates fc partials via atomics).
__global__ void init_kernel(int* wsi, float* out) {
  int idx = blockIdx.x * blockDim.x + threadIdx.x;
  int stride = gridDim.x * blockDim.x;
  const int nws = (HB_OFF + BATCH * HDIM * 2) / 4;  // bars + hbuf[0] (1 MB fp16)
  for (int i = idx; i < nws; i += stride) wsi[i] = 0;
  for (int i = idx; i < BATCH * PRED; i += stride) out[i] = 0.f;
}

__global__ __launch_bounds__(256, 1) void lstm_persist(
    const float* __restrict__ x,
    const float* __restrict__ w_ih,
    const float* __restrict__ w_hh,
    const float* __restrict__ b_ih,
    const float* __restrict__ b_hh,
    const float* __restrict__ w_fc,
    const float* __restrict__ b_fc,
    float* __restrict__ out,          // [1024][48] fp32; also decode input
    _Float16* __restrict__ hbuf,      // [2][1024][512] fp16 ping-pong
    Bar* __restrict__ bars)           // [32] group barriers
{
  const int bid  = blockIdx.x;
  const int grp  = bid & (NGRP - 1);  // group's 8 blocks land on one XCD (perf heuristic only)
  const int ub   = bid >> 5;          // unit-block 0..7
  const int tid  = threadIdx.x;
  const int wid  = tid >> 6;          // wave 0..3
  const int lane = tid & 63;
  const int quad = lane >> 4;
  const int lcol = lane & 15;
  const int b0   = grp * GBAT;
  const int myu  = ub * UBU + wid * 16 + lcol;   // this lane's hidden unit

  // h tile: 32 batches x 512 k, fp16, pitch 520 (2-way bank alias only -> free)
  __shared__ __align__(16) _Float16 hs[GBAT][520];

  // ---- one-time: this wave's weight tile as register B-fragments ----
  // B-frag layout (16x16x32): n = lane&15, k = kc*32 + quad*8 + j
  f16x8 wf[4][16];
  float wih[4], bias[4];
#pragma unroll
  for (int nt = 0; nt < 4; ++nt) {         // gate type i,f,g,o
    const int j = nt * HDIM + myu;
    wih[nt]  = w_ih[j];
    bias[nt] = b_ih[j] + b_hh[j];
#pragma unroll
    for (int kc = 0; kc < 16; ++kc) {
      const float* s = w_hh + (size_t)j * HDIM + kc * 32 + quad * 8;
      f16x8 v;
#pragma unroll
      for (int i = 0; i < 8; ++i) v[i] = (_Float16)s[i];
      wf[nt][kc] = v;
    }
  }
  const float wfc = w_fc[myu];
  const float bfc = b_fc[0];

  float cst[2][4];
#pragma unroll
  for (int mt = 0; mt < 2; ++mt)
#pragma unroll
    for (int r = 0; r < 4; ++r) cst[mt][r] = 0.f;

  Bar* bar = &bars[grp];

  for (int t = 0; t < STEPS; ++t) {
    const _Float16* hcur = hbuf + (size_t)(t & 1) * BATCH * HDIM;
    _Float16*       hnxt = hbuf + (size_t)((t + 1) & 1) * BATCH * HDIM;

    // ---- prefetch x_t (issued early; consumed in epilogue) ----
    // decode feedback must be a coherent (sc1) load: out was written by
    // other blocks' atomics at the memory-side coherence point.
    float xts[2][4];
#pragma unroll
    for (int mt = 0; mt < 2; ++mt)
#pragma unroll
      for (int r = 0; r < 4; ++r) {
        const int b = b0 + mt * 16 + quad * 4 + r;
        xts[mt][r] = (t < TENC)
            ? x[(size_t)b * TENC + t]
            : __hip_atomic_load(&out[b * PRED + (t - TENC)],
                                __ATOMIC_RELAXED, __HIP_MEMORY_SCOPE_AGENT);
      }

    // ---- stage h tile into LDS via coherent 8B loads (all 16 in flight) ----
    u64 tmp[16];
#pragma unroll
    for (int i = 0; i < 16; ++i) {
      const int e   = tid + i * 256;       // 4096 8B-chunks total
      const int row = e >> 7;              // 128 chunks per 512-half row
      const int c   = e & 127;
      tmp[i] = __hip_atomic_load(
          (const u64*)(hcur + (size_t)(b0 + row) * HDIM) + c,
          __ATOMIC_RELAXED, __HIP_MEMORY_SCOPE_AGENT);
    }
#pragma unroll
    for (int i = 0; i < 16; ++i) {
      const int e   = tid + i * 256;
      const int row = e >> 7;
      const int c   = e & 127;
      *reinterpret_cast<u64*>(&hs[row][c * 4]) = tmp[i];
    }
    __syncthreads();

    // ---- GEMM: acc[mt][nt] = h(32x512) @ w_tile.T ----
    f32x4 acc[2][4];
#pragma unroll
    for (int mt = 0; mt < 2; ++mt)
#pragma unroll
      for (int nt = 0; nt < 4; ++nt) acc[mt][nt] = (f32x4){0.f, 0.f, 0.f, 0.f};

#pragma unroll
    for (int kc = 0; kc < 16; ++kc) {
      f16x8 a0 = *reinterpret_cast<const f16x8*>(&hs[lcol][kc * 32 + quad * 8]);
      f16x8 a1 = *reinterpret_cast<const f16x8*>(&hs[16 + lcol][kc * 32 + quad * 8]);
#pragma unroll
      for (int nt = 0; nt < 4; ++nt) {
        acc[0][nt] = __builtin_amdgcn_mfma_f32_16x16x32_f16(a0, wf[nt][kc], acc[0][nt], 0, 0, 0);
        acc[1][nt] = __builtin_amdgcn_mfma_f32_16x16x32_f16(a1, wf[nt][kc], acc[1][nt], 0, 0, 0);
      }
    }

    // ---- cell update (C-layout: col=lane&15, row=quad*4+r) ----
    float hnew[2][4];
#pragma unroll
    for (int mt = 0; mt < 2; ++mt) {
#pragma unroll
      for (int r = 0; r < 4; ++r) {
        const int b = b0 + mt * 16 + quad * 4 + r;
        const float xt = xts[mt][r];
        const float gi = acc[mt][0][r] + xt * wih[0] + bias[0];
        const float gf = acc[mt][1][r] + xt * wih[1] + bias[1];
        const float gg = acc[mt][2][r] + xt * wih[2] + bias[2];
        const float go = acc[mt][3][r] + xt * wih[3] + bias[3];
        const float si = 1.f / (1.f + __expf(-gi));
        const float sf = 1.f / (1.f + __expf(-gf));
        const float so = 1.f / (1.f + __expf(-go));
        const float tg = 1.f - 2.f / (1.f + __expf(2.f * gg));   // tanh
        const float cn = sf * cst[mt][r] + si * tg;
        cst[mt][r] = cn;
        const float tc = 1.f - 2.f / (1.f + __expf(2.f * cn));   // tanh
        const float hn = so * tc;
        hnew[mt][r] = hn;

        // pack 4 adjacent units (same batch) across lanes -> one 8B sc1 store
        const unsigned short hb = __builtin_bit_cast(unsigned short, (_Float16)hn);
        const unsigned v0  = hb;
        const unsigned o0  = (unsigned)__shfl_xor((int)v0, 1);
        const unsigned p01 = (lcol & 1) ? ((v0 << 16) | o0) : ((o0 << 16) | v0);
        const unsigned q   = (unsigned)__shfl_xor((int)p01, 2);
        const u64 p4 = (lcol & 2) ? (((u64)p01 << 32) | (u64)q)
                                  : (((u64)q << 32) | (u64)p01);
        if ((lcol & 3) == ((mt * 4 + r) & 3)) {   // spread store duty
          _Float16* dst = hnxt + (size_t)b * HDIM + (ub * UBU + wid * 16 + (lcol & ~3));
          __hip_atomic_store((u64*)dst, p4, __ATOMIC_RELAXED, __HIP_MEMORY_SCOPE_AGENT);
        }
      }
    }

    // ---- fc(h) for decode steps ----
    if (t >= TENC - 1) {
      const int p = t - (TENC - 1);
#pragma unroll
      for (int mt = 0; mt < 2; ++mt) {
#pragma unroll
        for (int r = 0; r < 4; ++r) {
          float v = hnew[mt][r] * wfc;
          v += __shfl_xor(v, 1);
          v += __shfl_xor(v, 2);
          v += __shfl_xor(v, 4);
          v += __shfl_xor(v, 8);
          if (lcol == 0) {
            const int b = b0 + mt * 16 + quad * 4 + r;
            const float add = v + ((ub == 0 && wid == 0) ? bfc : 0.f);
            atomicAdd(&out[b * PRED + p], add);
          }
        }
      }
    }

    // ---- group barrier, fence-free ----
    // Every wave drains ITS OWN stores/atomics to the coherence point, then
    // block-level sync, then one arrival atomic. No wbl2/inv anywhere.
    asm volatile("s_waitcnt vmcnt(0)" ::: "memory");
    __syncthreads();
    if (tid == 0) {
      int old = __hip_atomic_fetch_add(&bar->count, 1, __ATOMIC_RELAXED,
                                       __HIP_MEMORY_SCOPE_AGENT);
      if (old == NUB - 1) {
        __hip_atomic_store(&bar->count, 0, __ATOMIC_RELAXED, __HIP_MEMORY_SCOPE_AGENT);
        asm volatile("s_waitcnt vmcnt(0)" ::: "memory");  // reset lands before gen
        __hip_atomic_fetch_add(&bar->gen, 1, __ATOMIC_RELAXED, __HIP_MEMORY_SCOPE_AGENT);
      } else {
        while (__hip_atomic_load(&bar->gen, __ATOMIC_RELAXED,
                                 __HIP_MEMORY_SCOPE_AGENT) < t + 1)
          __builtin_amdgcn_s_sleep(1);
      }
    }
    __syncthreads();
  }
}

extern "C" void kernel_launch(void* const* d_in, const int* in_sizes, int n_in,
                              void* d_out, int out_size, void* d_ws, size_t ws_size,
                              hipStream_t stream) {
  const float* x    = (const float*)d_in[0];
  const float* w_ih = (const float*)d_in[1];
  const float* w_hh = (const float*)d_in[2];
  const float* b_ih = (const float*)d_in[3];
  const float* b_hh = (const float*)d_in[4];
  const float* w_fc = (const float*)d_in[5];
  const float* b_fc = (const float*)d_in[6];
  float* out = (float*)d_out;
  Bar* bars = (Bar*)d_ws;
  _Float16* hbuf = (_Float16*)((char*)d_ws + HB_OFF);

  hipLaunchKernelGGL(init_kernel, dim3(256), dim3(256), 0, stream, (int*)d_ws, out);
  hipLaunchKernelGGL(lstm_persist, dim3(NGRP * NUB), dim3(256), 0, stream,
                     x, w_ih, w_hh, b_ih, b_hh, w_fc, b_fc, out, hbuf, bars);
}